// Round 9
// baseline (44.101 us; speedup 1.0000x reference)
//
#include <hip/hip_runtime.h>

typedef __attribute__((ext_vector_type(8))) short s8v;   // 8 x bf16 (bit pattern)
typedef __attribute__((ext_vector_type(4))) float f4v;

__device__ __forceinline__ float sgm(float x) { return 1.f / (1.f + __expf(-x)); }
__device__ __forceinline__ float tanh_fast(float x) {
    float e = __expf(-2.f * fabsf(x));
    float t = (1.f - e) / (1.f + e);
    return copysignf(t, x);
}
// split f32 -> bf16 hi + bf16 lo (x ~= hi + lo, residual ~2^-17 |x|)
__device__ __forceinline__ void bsplit(float x, short& hi, short& lo) {
    unsigned u = __float_as_uint(x);
    unsigned hb = u & 0xffff0000u;
    hi = (short)(hb >> 16);
    float r = x - __uint_as_float(hb);
    lo = (short)(__float_as_uint(r) >> 16);
}

#define SQ 5     // seqs per block; 480 blocks x 5 = 2400 (300 % 5 == 0 -> one b per block)

// z-tile slice via MFMA, bf16 hi/lo split: Wh*vh + Wl*vh + Wh*vl.
// B/D layout conventions HW-verified rounds 6-8 (absmax 0.0039 vs np ref).
__device__ __forceinline__ f4v zA(const short* vh, const short* vl,
    const s8v (&ah)[2], const s8v (&al)[2], f4v bias, int boff, int g)
{
    s8v bh0 = *(const s8v*)((const char*)vh + boff +      g*16);
    s8v bh1 = *(const s8v*)((const char*)vh + boff + 64 + g*16);
    s8v bl0 = *(const s8v*)((const char*)vl + boff +      g*16);
    s8v bl1 = *(const s8v*)((const char*)vl + boff + 64 + g*16);
    f4v acc = bias;
    acc = __builtin_amdgcn_mfma_f32_16x16x32_bf16(ah[0], bh0, acc, 0, 0, 0);
    acc = __builtin_amdgcn_mfma_f32_16x16x32_bf16(ah[1], bh1, acc, 0, 0, 0);
    acc = __builtin_amdgcn_mfma_f32_16x16x32_bf16(al[0], bh0, acc, 0, 0, 0);
    acc = __builtin_amdgcn_mfma_f32_16x16x32_bf16(al[1], bh1, acc, 0, 0, 0);
    acc = __builtin_amdgcn_mfma_f32_16x16x32_bf16(ah[0], bl0, acc, 0, 0, 0);
    acc = __builtin_amdgcn_mfma_f32_16x16x32_bf16(ah[1], bl1, acc, 0, 0, 0);
    return acc;
}

// ===== single fused kernel: nbr + GAT attention + LSTM x2 (MFMA, in-lane update) + FC =====
// 480 blocks x 512 thr (8 waves), SQ=5 seqs/block -> ~2 blocks/CU.
// A-rows permuted so lane (n16,g) of wave w gets D = {zi,zf,zg,zo} of cell w*4+g, seq n16:
//   frag row q (=n16) <- W row (q&3)*32 + w*4 + (q>>2); D slot (g,r) -> gate r, cell w*4+g.
__global__ __launch_bounds__(512, 4) void k_stgat(
    const float* __restrict__ A,    const float* __restrict__ X,
    const float* __restrict__ Wg,   const float* __restrict__ aat,
    const float* __restrict__ Wih0, const float* __restrict__ Whh0,
    const float* __restrict__ bih0, const float* __restrict__ bhh0,
    const float* __restrict__ Wih1, const float* __restrict__ Whh1,
    const float* __restrict__ bih1, const float* __restrict__ bhh1,
    const float* __restrict__ fcW,  const float* __restrict__ fcb,
    float* __restrict__ out)
{
    __shared__ int   snbr[SQ][64];
    __shared__ int   scnt[SQ];
    __shared__ float shg[SQ*384];                        // local hgat (7.5 KB)
    __shared__ __align__(16) char uarea[43200];          // phase B: X[b] slice (10800 f)
                                                         // phase C: vh0|vl0|vh1|vl1|sh1f
    const int tid  = threadIdx.x;
    const int w    = tid >> 6;        // wave 0..7
    const int l    = tid & 63;
    const int seq0 = blockIdx.x * SQ;
    const int b    = seq0 / 300, i0 = seq0 - b*300;

    float* Xs = (float*)uarea;

    // ---------- phase A: cooperative X[b] slice load + neighbor lists ----------
    {
        const float* Xg = X + (size_t)b * 10800;
        for (int x = tid; x < 10800; x += 512) Xs[x] = Xg[x];
    }
    if (w < SQ) {                     // wave w builds neighbor list of row i0+w
        int i = i0 + w;
        int c = 0;
        for (int j0 = 0; j0 < 300; j0 += 64) {
            int j = j0 + l;
            bool p = (j < 300) && (A[i*300 + j] != 0.f);
            unsigned long long m = __ballot(p);
            if (p) {
                int pos = __popcll(m & ((1ull << l) - 1ull));
                if (c + pos < 64) snbr[w][c + pos] = j;
            }
            c += __popcll(m);
        }
        if (c > 64) c = 64;
        if (l == 0) scnt[w] = c;
    }

    // ---------- LSTM A-fragments (permuted rows), resident in VGPRs all kernel ----------
    const int n16 = l & 15;           // B/D col = seq slot ; A frag row
    const int g   = l >> 4;           // k-group 0..3 ; D row-quad
    const int cc  = w*4 + g;          // cell owned by this lane in the update
    const int arow = (n16 & 3)*32 + w*4 + (n16 >> 2);    // permuted W row
    s8v a0h[2], a0l[2], a1h[2], a1l[2];
    {
        const float* s00 = Wih0 + arow*32 + g*8;
        const float* s01 = Whh0 + arow*32 + g*8;
        const float* s10 = Wih1 + arow*32 + g*8;
        const float* s11 = Whh1 + arow*32 + g*8;
        #pragma unroll
        for (int j = 0; j < 8; j++) {
            short hh, ll;
            bsplit(s00[j], hh, ll); a0h[0][j]=hh; a0l[0][j]=ll;
            bsplit(s01[j], hh, ll); a0h[1][j]=hh; a0l[1][j]=ll;
            bsplit(s10[j], hh, ll); a1h[0][j]=hh; a1l[0][j]=ll;
            bsplit(s11[j], hh, ll); a1h[1][j]=hh; a1l[1][j]=ll;
        }
    }
    f4v bias0, bias1;                 // D slot r = gate r of cell cc
    #pragma unroll
    for (int r = 0; r < 4; r++) {
        int br = r*32 + cc;
        bias0[r] = bih0[br] + bhh0[br];
        bias1[r] = bih1[br] + bhh1[br];
    }

    __syncthreads();

    // ---------- phase B: GAT attention from LDS; 60 (seq,t) units over 8 waves ----------
    {
        const int h = l >> 3, j8 = l & 7, d = j8 & 3;
        float wal0=0.f, wal1=0.f, wal2=0.f, war0=0.f, war1=0.f, war2=0.f;
        #pragma unroll
        for (int dd = 0; dd < 4; dd++) {
            float av = aat[dd], bv = aat[4+dd];
            const float* wr = Wg + (h*4+dd)*3;
            wal0 += wr[0]*av; wal1 += wr[1]*av; wal2 += wr[2]*av;
            war0 += wr[0]*bv; war1 += wr[1]*bv; war2 += wr[2]*bv;
        }
        const float* wp = Wg + (h*4+d)*3;
        float wp0 = wp[0], wp1 = wp[1], wp2 = wp[2];

        for (int u = w; u < SQ*12; u += 8) {
            int us = u / 12, t = u - us*12;
            int i = i0 + us;
            int c = scnt[us];

            const float* Xi = Xs + i*36 + t*3;
            float gl = Xi[0]*wal0 + Xi[1]*wal1 + Xi[2]*wal2;

            float m = -1e30f, s = 0.f, a0 = 0.f, a1 = 0.f, a2 = 0.f;
            for (int kk = j8; kk < c; kk += 8) {
                int j = snbr[us][kk];
                const float* Xj = Xs + j*36 + t*3;
                float y0 = Xj[0], y1 = Xj[1], y2 = Xj[2];
                float e = gl + y0*war0 + y1*war1 + y2*war2;
                e = e > 0.f ? e : 0.2f*e;      // leaky_relu 0.2
                if (e > m) {
                    float sc = __expf(m - e);
                    s = s*sc + 1.f;
                    a0 = a0*sc + y0; a1 = a1*sc + y1; a2 = a2*sc + y2;
                    m = e;
                } else {
                    float wt = __expf(e - m);
                    s += wt;
                    a0 += wt*y0; a1 += wt*y1; a2 += wt*y2;
                }
            }
            #pragma unroll
            for (int off = 1; off <= 4; off <<= 1) {
                float m2 = __shfl_xor(m, off, 64);
                float s2 = __shfl_xor(s, off, 64);
                float b0 = __shfl_xor(a0, off, 64);
                float b1 = __shfl_xor(a1, off, 64);
                float b2 = __shfl_xor(a2, off, 64);
                float mo = fmaxf(m, m2);
                float w1 = __expf(m - mo), w2 = __expf(m2 - mo);
                s = s*w1 + s2*w2;
                a0 = a0*w1 + b0*w2; a1 = a1*w1 + b1*w2; a2 = a2*w1 + b2*w2;
                m = mo;
            }
            if (j8 < 4)
                shg[us*384 + t*32 + h*4 + d] = (a0*wp0 + a1*wp1 + a2*wp2) / s;
        }
    }
    __syncthreads();                  // Xs dead from here; reuse uarea for v-bufs

    // ---------- phase C: MFMA LSTM with in-lane cell update ----------
    short* vh0 = (short*)uarea;                   // [seq16][x(t) ; h0(t-1)] hi
    short* vl0 = vh0 + 16*72;                     // lo
    short* vh1 = vl0 + 16*72;                     // [seq16][h0(t) ; h1(t-1)] hi
    short* vl1 = vh1 + 16*72;                     // lo
    float* sh1f = (float*)(vl1 + 16*72);          // final h1 for FC

    for (int x = tid; x < 16*72; x += 512) {
        vh0[x] = 0; vl0[x] = 0; vh1[x] = 0; vl1[x] = 0;
    }
    __syncthreads();
    if (tid < SQ*32) {                            // x(0)
        int us = tid >> 5, uc = tid & 31;
        short hh, ll; bsplit(shg[us*384 + uc], hh, ll);
        vh0[us*72 + uc] = hh;  vl0[us*72 + uc] = ll;
    }
    __syncthreads();

    const int boff = n16 * 144;
    float c0 = 0.f, c1 = 0.f;

    // prologue: z0(0) -> upd0(0)
    {
        f4v z = zA(vh0, vl0, a0h, a0l, bias0, boff, g);
        __syncthreads();
        c0 = sgm(z[1])*c0 + sgm(z[0])*tanh_fast(z[2]);
        float h0v = sgm(z[3])*tanh_fast(c0);
        short hh, ll; bsplit(h0v, hh, ll);
        vh0[n16*72 + 32 + cc] = hh;  vl0[n16*72 + 32 + cc] = ll;
        vh1[n16*72 + cc]      = hh;  vl1[n16*72 + cc]      = ll;
        if (tid < SQ*32) {                        // stage x(1)
            int us = tid >> 5, uc = tid & 31;
            bsplit(shg[us*384 + 32 + uc], hh, ll);
            vh0[us*72 + uc] = hh;  vl0[us*72 + uc] = ll;
        }
        __syncthreads();
    }

    for (int t = 0; t < 12; t++) {
        f4v z1 = zA(vh1, vl1, a1h, a1l, bias1, boff, g);        // z1(t)
        f4v z0;
        if (t < 11)
            z0 = zA(vh0, vl0, a0h, a0l, bias0, boff, g);        // z0(t+1)
        __syncthreads();
        // upd1(t) — fully in-lane
        c1 = sgm(z1[1])*c1 + sgm(z1[0])*tanh_fast(z1[2]);
        float h1v = sgm(z1[3])*tanh_fast(c1);
        short hh, ll; bsplit(h1v, hh, ll);
        vh1[n16*72 + 32 + cc] = hh;  vl1[n16*72 + 32 + cc] = ll;
        if (t == 11) {
            if (n16 < SQ) sh1f[n16*32 + cc] = h1v;
        } else {
            // upd0(t+1)
            c0 = sgm(z0[1])*c0 + sgm(z0[0])*tanh_fast(z0[2]);
            float h0v = sgm(z0[3])*tanh_fast(c0);
            bsplit(h0v, hh, ll);
            vh0[n16*72 + 32 + cc] = hh;  vl0[n16*72 + 32 + cc] = ll;
            vh1[n16*72 + cc]      = hh;  vl1[n16*72 + cc]      = ll;
            if (tid < SQ*32 && t + 2 < 12) {                    // stage x(t+2)
                int us = tid >> 5, uc = tid & 31;
                short h2, l2; bsplit(shg[us*384 + (t+2)*32 + uc], h2, l2);
                vh0[us*72 + uc] = h2;  vl0[us*72 + uc] = l2;
            }
        }
        __syncthreads();
    }

    // ---- FC: 180 outputs (5 seqs x 36) ----
    if (tid < SQ*36) {
        int s = tid / 36, r = tid - s*36;
        float acc = fcb[r];
        #pragma unroll
        for (int c4 = 0; c4 < 8; c4++) {
            float4 uv = *(const float4*)&fcW[r*32 + 4*c4];
            acc += uv.x*sh1f[s*32+4*c4+0] + uv.y*sh1f[s*32+4*c4+1]
                 + uv.z*sh1f[s*32+4*c4+2] + uv.w*sh1f[s*32+4*c4+3];
        }
        out[(seq0 + s)*36 + r] = acc;
    }
}

extern "C" void kernel_launch(void* const* d_in, const int* in_sizes, int n_in,
                              void* d_out, int out_size, void* d_ws, size_t ws_size,
                              hipStream_t stream)
{
    const float* A    = (const float*)d_in[0];
    const float* X    = (const float*)d_in[1];
    const float* Wg   = (const float*)d_in[2];
    const float* aat  = (const float*)d_in[3];
    const float* Wih0 = (const float*)d_in[4];
    const float* Whh0 = (const float*)d_in[5];
    const float* bih0 = (const float*)d_in[6];
    const float* bhh0 = (const float*)d_in[7];
    const float* Wih1 = (const float*)d_in[8];
    const float* Whh1 = (const float*)d_in[9];
    const float* bih1 = (const float*)d_in[10];
    const float* bhh1 = (const float*)d_in[11];
    const float* fcW  = (const float*)d_in[12];
    const float* fcb  = (const float*)d_in[13];
    float* out = (float*)d_out;

    k_stgat<<<480, 512, 0, stream>>>(A, X, Wg, aat,
                                     Wih0, Whh0, bih0, bhh0,
                                     Wih1, Whh1, bih1, bhh1,
                                     fcW, fcb, out);
}

// Round 10
// 36.822 us; speedup vs baseline: 1.1977x; 1.1977x over previous
//
#include <hip/hip_runtime.h>

typedef __attribute__((ext_vector_type(8))) short s8v;   // 8 x bf16 (bit pattern)
typedef __attribute__((ext_vector_type(4))) float f4v;

__device__ __forceinline__ float sgm(float x) { return 1.f / (1.f + __expf(-x)); }
__device__ __forceinline__ float tanhq(float x) { return 2.f / (1.f + __expf(-2.f*x)) - 1.f; }
// split f32 -> bf16 hi + bf16 lo (x ~= hi + lo, residual ~2^-17 |x|)
__device__ __forceinline__ void bsplit(float x, short& hi, short& lo) {
    unsigned u = __float_as_uint(x);
    unsigned hb = u & 0xffff0000u;
    hi = (short)(hb >> 16);
    float r = x - __uint_as_float(hb);
    lo = (short)(__float_as_uint(r) >> 16);
}
// quad_perm DPP adds (VALU, not DS): xor1 = [1,0,3,2] = 0xB1 ; xor2 = [2,3,0,1] = 0x4E
__device__ __forceinline__ float dppadd1(float x) {
    return x + __uint_as_float(__builtin_amdgcn_mov_dpp(__float_as_uint(x), 0xB1, 0xF, 0xF, true));
}
__device__ __forceinline__ float dppadd2(float x) {
    return x + __uint_as_float(__builtin_amdgcn_mov_dpp(__float_as_uint(x), 0x4E, 0xF, 0xF, true));
}

#define SQ 5     // seqs per block; 480 blocks x 5 = 2400 (same b per block)

// Two 16x16 z-tiles per wave (M=32): D_A = gates of cell w*8+g, D_B = cell w*8+4+g.
// B/D layout + row-permutation HW-verified rounds 6-9 (absmax 0.0039 vs np ref).
__device__ __forceinline__ void zA2(const short* vh, const short* vl,
    const s8v (&ah)[2][2], const s8v (&al)[2][2], const f4v (&bias)[2],
    int boff, int g, f4v& dA, f4v& dB)
{
    s8v bh0 = *(const s8v*)((const char*)vh + boff +      g*16);
    s8v bh1 = *(const s8v*)((const char*)vh + boff + 64 + g*16);
    s8v bl0 = *(const s8v*)((const char*)vl + boff +      g*16);
    s8v bl1 = *(const s8v*)((const char*)vl + boff + 64 + g*16);
    dA = bias[0];
    dA = __builtin_amdgcn_mfma_f32_16x16x32_bf16(ah[0][0], bh0, dA, 0, 0, 0);
    dA = __builtin_amdgcn_mfma_f32_16x16x32_bf16(ah[0][1], bh1, dA, 0, 0, 0);
    dA = __builtin_amdgcn_mfma_f32_16x16x32_bf16(al[0][0], bh0, dA, 0, 0, 0);
    dA = __builtin_amdgcn_mfma_f32_16x16x32_bf16(al[0][1], bh1, dA, 0, 0, 0);
    dA = __builtin_amdgcn_mfma_f32_16x16x32_bf16(ah[0][0], bl0, dA, 0, 0, 0);
    dA = __builtin_amdgcn_mfma_f32_16x16x32_bf16(ah[0][1], bl1, dA, 0, 0, 0);
    dB = bias[1];
    dB = __builtin_amdgcn_mfma_f32_16x16x32_bf16(ah[1][0], bh0, dB, 0, 0, 0);
    dB = __builtin_amdgcn_mfma_f32_16x16x32_bf16(ah[1][1], bh1, dB, 0, 0, 0);
    dB = __builtin_amdgcn_mfma_f32_16x16x32_bf16(al[1][0], bh0, dB, 0, 0, 0);
    dB = __builtin_amdgcn_mfma_f32_16x16x32_bf16(al[1][1], bh1, dB, 0, 0, 0);
    dB = __builtin_amdgcn_mfma_f32_16x16x32_bf16(ah[1][0], bl0, dB, 0, 0, 0);
    dB = __builtin_amdgcn_mfma_f32_16x16x32_bf16(ah[1][1], bl1, dB, 0, 0, 0);
}

// ===== single fused kernel: nbr + GAT attention + LSTM x2 (MFMA waves 0-3) + FC =====
__global__ __launch_bounds__(512, 4) void k_stgat(
    const float* __restrict__ A,    const float* __restrict__ X,
    const float* __restrict__ Wg,   const float* __restrict__ aat,
    const float* __restrict__ Wih0, const float* __restrict__ Whh0,
    const float* __restrict__ bih0, const float* __restrict__ bhh0,
    const float* __restrict__ Wih1, const float* __restrict__ Whh1,
    const float* __restrict__ bih1, const float* __restrict__ bhh1,
    const float* __restrict__ fcW,  const float* __restrict__ fcb,
    float* __restrict__ out)
{
    __shared__ int   snbr[SQ][64];
    __shared__ int   scnt[SQ];
    __shared__ float shg[SQ*384];                        // local hgat (7.5 KB)
    __shared__ __align__(16) char uarea[43200];          // B: X[b] slice ; C: v bufs + sh1f

    const int tid  = threadIdx.x;
    const int w    = tid >> 6;        // wave 0..7
    const int l    = tid & 63;
    const int seq0 = blockIdx.x * SQ;
    const int b    = seq0 / 300, i0 = seq0 - b*300;

    float* Xs = (float*)uarea;

    // ---------- phase A: cooperative X[b] slice load + neighbor lists ----------
    {
        const float* Xg = X + (size_t)b * 10800;
        for (int x = tid; x < 10800; x += 512) Xs[x] = Xg[x];
    }
    if (w < SQ) {                     // wave w builds neighbor list of row i0+w
        int i = i0 + w;
        int c = 0;
        for (int j0 = 0; j0 < 300; j0 += 64) {
            int j = j0 + l;
            bool p = (j < 300) && (A[i*300 + j] != 0.f);
            unsigned long long m = __ballot(p);
            if (p) {
                int pos = __popcll(m & ((1ull << l) - 1ull));
                if (c + pos < 64) snbr[w][c + pos] = j;
            }
            c += __popcll(m);
        }
        if (c > 64) c = 64;
        if (l == 0) scnt[w] = c;
    }
    __syncthreads();

    // ---------- phase B: GAT attention (all 8 waves); waves 4-7 take 8 units, 0-3 take 7 ----------
    {
        const int hh = l >> 3, j8 = l & 7, dd = j8 & 3;
        float wal0=0.f, wal1=0.f, wal2=0.f, war0=0.f, war1=0.f, war2=0.f;
        #pragma unroll
        for (int d4 = 0; d4 < 4; d4++) {
            float av = aat[d4], bv = aat[4+d4];
            const float* wr = Wg + (hh*4+d4)*3;
            wal0 += wr[0]*av; wal1 += wr[1]*av; wal2 += wr[2]*av;
            war0 += wr[0]*bv; war1 += wr[1]*bv; war2 += wr[2]*bv;
        }
        const float* wp = Wg + (hh*4+dd)*3;
        float wp0 = wp[0], wp1 = wp[1], wp2 = wp[2];

        for (int u = 7 - w; u < SQ*12; u += 8) {
            int us = u / 12, t = u - us*12;
            int i = i0 + us;
            int c = scnt[us];

            const float* Xi = Xs + i*36 + t*3;
            float gl = Xi[0]*wal0 + Xi[1]*wal1 + Xi[2]*wal2;

            // max-free softmax: e bounded (~|e|<12), exp safe in f32; branchless
            float s = 0.f, a0 = 0.f, a1 = 0.f, a2 = 0.f;
            for (int kk = j8; kk < c; kk += 8) {
                int j = snbr[us][kk];
                const float* Xj = Xs + j*36 + t*3;
                float y0 = Xj[0], y1 = Xj[1], y2 = Xj[2];
                float e = gl + y0*war0 + y1*war1 + y2*war2;
                e = e > 0.f ? e : 0.2f*e;      // leaky_relu 0.2
                float wt = __expf(e);
                s += wt; a0 += wt*y0; a1 += wt*y1; a2 += wt*y2;
            }
            // add-merge across 8 j-slots: xor1/xor2 via DPP (VALU), xor4 via shfl
            s  = dppadd1(s);  a0 = dppadd1(a0); a1 = dppadd1(a1); a2 = dppadd1(a2);
            s  = dppadd2(s);  a0 = dppadd2(a0); a1 = dppadd2(a1); a2 = dppadd2(a2);
            s  += __shfl_xor(s, 4, 64);
            a0 += __shfl_xor(a0, 4, 64);
            a1 += __shfl_xor(a1, 4, 64);
            a2 += __shfl_xor(a2, 4, 64);
            if (j8 < 4)
                shg[us*384 + t*32 + hh*4 + dd] = (a0*wp0 + a1*wp1 + a2*wp2) / s;
        }
    }

    // ---------- A-fragments for waves 0-3 (regs only; overlaps waves 4-7's extra B units) ----------
    const int n16 = l & 15;           // B/D col = seq slot ; A frag row
    const int g   = l >> 4;           // k-group ; D row-quad
    const int cA  = w*8 + g;          // cells owned by this lane (w<4)
    const int cB  = w*8 + 4 + g;
    s8v a0h[2][2], a0l[2][2], a1h[2][2], a1l[2][2];
    f4v bias0[2], bias1[2];
    if (w < 4) {
        #pragma unroll
        for (int tau = 0; tau < 2; tau++) {
            const int arow = (n16 & 3)*32 + w*8 + tau*4 + (n16 >> 2);   // permuted W row
            const float* s00 = Wih0 + arow*32 + g*8;
            const float* s01 = Whh0 + arow*32 + g*8;
            const float* s10 = Wih1 + arow*32 + g*8;
            const float* s11 = Whh1 + arow*32 + g*8;
            #pragma unroll
            for (int j = 0; j < 8; j++) {
                short hh2, ll2;
                bsplit(s00[j], hh2, ll2); a0h[tau][0][j]=hh2; a0l[tau][0][j]=ll2;
                bsplit(s01[j], hh2, ll2); a0h[tau][1][j]=hh2; a0l[tau][1][j]=ll2;
                bsplit(s10[j], hh2, ll2); a1h[tau][0][j]=hh2; a1l[tau][0][j]=ll2;
                bsplit(s11[j], hh2, ll2); a1h[tau][1][j]=hh2; a1l[tau][1][j]=ll2;
            }
            const int cell = w*8 + tau*4 + g;
            #pragma unroll
            for (int r = 0; r < 4; r++) {
                bias0[tau][r] = bih0[r*32+cell] + bhh0[r*32+cell];
                bias1[tau][r] = bih1[r*32+cell] + bhh1[r*32+cell];
            }
        }
    }
    __syncthreads();                  // Xs dead; uarea becomes v buffers

    // ---------- phase C: MFMA LSTM (waves 0-3) with in-lane update; x-staging on waves 4-5 ----------
    short* vh0 = (short*)uarea;                   // [seq16][x(t) ; h0(t-1)] hi
    short* vl0 = vh0 + 16*72;
    short* vh1 = vl0 + 16*72;                     // [seq16][h0(t) ; h1(t-1)] hi
    short* vl1 = vh1 + 16*72;
    float* sh1f = (float*)(vl1 + 16*72);          // final h1 for FC

    {   // zero all v buffers (2304 dwords)
        unsigned* vz = (unsigned*)uarea;
        for (int x = tid; x < 2304; x += 512) vz[x] = 0;
    }
    __syncthreads();
    if (tid >= 256 && tid < 416) {                // waves 4-5: stage x(0)
        int us = (tid - 256) >> 5, uc = tid & 31;
        short hh2, ll2; bsplit(shg[us*384 + uc], hh2, ll2);
        vh0[us*72 + uc] = hh2;  vl0[us*72 + uc] = ll2;
    }
    __syncthreads();

    const int boff = n16 * 144;
    float c0A = 0.f, c0B = 0.f, c1A = 0.f, c1B = 0.f;

    auto cellup = [&](f4v z, float& cs) -> float {
        cs = sgm(z[1])*cs + sgm(z[0])*tanhq(z[2]);
        return sgm(z[3])*tanhq(cs);
    };
    auto wr_h0 = [&](float hv, int c) {
        short hh2, ll2; bsplit(hv, hh2, ll2);
        vh0[n16*72 + 32 + c] = hh2;  vl0[n16*72 + 32 + c] = ll2;
        vh1[n16*72 + c]      = hh2;  vl1[n16*72 + c]      = ll2;
    };
    auto wr_h1 = [&](float hv, int c) {
        short hh2, ll2; bsplit(hv, hh2, ll2);
        vh1[n16*72 + 32 + c] = hh2;  vl1[n16*72 + 32 + c] = ll2;
    };

    // prologue: z0(0) -> upd0(0), stage x(1)
    {
        f4v zpA, zpB;
        if (w < 4) zA2(vh0, vl0, a0h, a0l, bias0, boff, g, zpA, zpB);
        __syncthreads();
        if (w < 4) {
            wr_h0(cellup(zpA, c0A), cA);
            wr_h0(cellup(zpB, c0B), cB);
        }
        if (tid >= 256 && tid < 416) {
            int us = (tid - 256) >> 5, uc = tid & 31;
            short hh2, ll2; bsplit(shg[us*384 + 32 + uc], hh2, ll2);
            vh0[us*72 + uc] = hh2;  vl0[us*72 + uc] = ll2;
        }
        __syncthreads();
    }

    for (int t = 0; t < 12; t++) {
        f4v z1A, z1B, z0A, z0B;
        if (w < 4) {
            zA2(vh1, vl1, a1h, a1l, bias1, boff, g, z1A, z1B);          // z1(t)
            if (t < 11)
                zA2(vh0, vl0, a0h, a0l, bias0, boff, g, z0A, z0B);      // z0(t+1)
        }
        __syncthreads();
        if (w < 4) {
            float h1a = cellup(z1A, c1A);                               // upd1(t)
            float h1b = cellup(z1B, c1B);
            wr_h1(h1a, cA);  wr_h1(h1b, cB);
            if (t == 11) {
                if (n16 < SQ) { sh1f[n16*32 + cA] = h1a; sh1f[n16*32 + cB] = h1b; }
            } else {
                wr_h0(cellup(z0A, c0A), cA);                            // upd0(t+1)
                wr_h0(cellup(z0B, c0B), cB);
            }
        }
        if (tid >= 256 && tid < 416 && t < 10) {                        // stage x(t+2)
            int us = (tid - 256) >> 5, uc = tid & 31;
            short hh2, ll2; bsplit(shg[us*384 + (t+2)*32 + uc], hh2, ll2);
            vh0[us*72 + uc] = hh2;  vl0[us*72 + uc] = ll2;
        }
        __syncthreads();
    }

    // ---- FC: 180 outputs (5 seqs x 36) ----
    if (tid < SQ*36) {
        int s = tid / 36, r = tid - s*36;
        float acc = fcb[r];
        #pragma unroll
        for (int c4 = 0; c4 < 8; c4++) {
            float4 uv = *(const float4*)&fcW[r*32 + 4*c4];
            acc += uv.x*sh1f[s*32+4*c4+0] + uv.y*sh1f[s*32+4*c4+1]
                 + uv.z*sh1f[s*32+4*c4+2] + uv.w*sh1f[s*32+4*c4+3];
        }
        out[(seq0 + s)*36 + r] = acc;
    }
}

extern "C" void kernel_launch(void* const* d_in, const int* in_sizes, int n_in,
                              void* d_out, int out_size, void* d_ws, size_t ws_size,
                              hipStream_t stream)
{
    const float* A    = (const float*)d_in[0];
    const float* X    = (const float*)d_in[1];
    const float* Wg   = (const float*)d_in[2];
    const float* aat  = (const float*)d_in[3];
    const float* Wih0 = (const float*)d_in[4];
    const float* Whh0 = (const float*)d_in[5];
    const float* bih0 = (const float*)d_in[6];
    const float* bhh0 = (const float*)d_in[7];
    const float* Wih1 = (const float*)d_in[8];
    const float* Whh1 = (const float*)d_in[9];
    const float* bih1 = (const float*)d_in[10];
    const float* bhh1 = (const float*)d_in[11];
    const float* fcW  = (const float*)d_in[12];
    const float* fcb  = (const float*)d_in[13];
    float* out = (float*)d_out;

    k_stgat<<<480, 512, 0, stream>>>(A, X, Wg, aat,
                                     Wih0, Whh0, bih0, bhh0,
                                     Wih1, Whh1, bih1, bhh1,
                                     fcW, fcb, out);
}

// Round 11
// 36.398 us; speedup vs baseline: 1.2116x; 1.0116x over previous
//
#include <hip/hip_runtime.h>

typedef __attribute__((ext_vector_type(8))) short s8v;   // 8 x bf16 (bit pattern)
typedef __attribute__((ext_vector_type(4))) float f4v;

__device__ __forceinline__ float sgm(float x) { return 1.f / (1.f + __expf(-x)); }
__device__ __forceinline__ float tanhq(float x) { return 2.f / (1.f + __expf(-2.f*x)) - 1.f; }
// split f32 -> bf16 hi + bf16 lo (x ~= hi + lo, residual ~2^-17 |x|)
__device__ __forceinline__ void bsplit(float x, short& hi, short& lo) {
    unsigned u = __float_as_uint(x);
    unsigned hb = u & 0xffff0000u;
    hi = (short)(hb >> 16);
    float r = x - __uint_as_float(hb);
    lo = (short)(__float_as_uint(r) >> 16);
}
// quad_perm DPP adds (VALU, not DS): xor1 = 0xB1 ; xor2 = 0x4E
__device__ __forceinline__ float dppadd1(float x) {
    return x + __uint_as_float(__builtin_amdgcn_mov_dpp(__float_as_uint(x), 0xB1, 0xF, 0xF, true));
}
__device__ __forceinline__ float dppadd2(float x) {
    return x + __uint_as_float(__builtin_amdgcn_mov_dpp(__float_as_uint(x), 0x4E, 0xF, 0xF, true));
}

#define SQ 5     // seqs per block; 480 blocks x 5 = 2400 (same b per block)

// Two 16x16 z-tiles per wave (M=32): D_A = gates of cell wl*8+g, D_B = cell wl*8+4+g.
// B/D layout + row-permutation HW-verified rounds 6-10 (absmax 0.0039 vs np ref).
__device__ __forceinline__ void zA2(const short* vh, const short* vl,
    const s8v (&ah)[2][2], const s8v (&al)[2][2], const f4v (&bias)[2],
    int boff, int g, f4v& dA, f4v& dB)
{
    s8v bh0 = *(const s8v*)((const char*)vh + boff +      g*16);
    s8v bh1 = *(const s8v*)((const char*)vh + boff + 64 + g*16);
    s8v bl0 = *(const s8v*)((const char*)vl + boff +      g*16);
    s8v bl1 = *(const s8v*)((const char*)vl + boff + 64 + g*16);
    dA = bias[0];
    dA = __builtin_amdgcn_mfma_f32_16x16x32_bf16(ah[0][0], bh0, dA, 0, 0, 0);
    dA = __builtin_amdgcn_mfma_f32_16x16x32_bf16(ah[0][1], bh1, dA, 0, 0, 0);
    dA = __builtin_amdgcn_mfma_f32_16x16x32_bf16(al[0][0], bh0, dA, 0, 0, 0);
    dA = __builtin_amdgcn_mfma_f32_16x16x32_bf16(al[0][1], bh1, dA, 0, 0, 0);
    dA = __builtin_amdgcn_mfma_f32_16x16x32_bf16(ah[0][0], bl0, dA, 0, 0, 0);
    dA = __builtin_amdgcn_mfma_f32_16x16x32_bf16(ah[0][1], bl1, dA, 0, 0, 0);
    dB = bias[1];
    dB = __builtin_amdgcn_mfma_f32_16x16x32_bf16(ah[1][0], bh0, dB, 0, 0, 0);
    dB = __builtin_amdgcn_mfma_f32_16x16x32_bf16(ah[1][1], bh1, dB, 0, 0, 0);
    dB = __builtin_amdgcn_mfma_f32_16x16x32_bf16(al[1][0], bh0, dB, 0, 0, 0);
    dB = __builtin_amdgcn_mfma_f32_16x16x32_bf16(al[1][1], bh1, dB, 0, 0, 0);
    dB = __builtin_amdgcn_mfma_f32_16x16x32_bf16(ah[1][0], bl0, dB, 0, 0, 0);
    dB = __builtin_amdgcn_mfma_f32_16x16x32_bf16(ah[1][1], bl1, dB, 0, 0, 0);
}

// ===== fused kernel: nbr + GAT attn + LSTM x2 (layer-split MFMA, dbuf, 1 barrier/phase) + FC =====
__global__ __launch_bounds__(512, 4) void k_stgat(
    const float* __restrict__ A,    const float* __restrict__ X,
    const float* __restrict__ Wg,   const float* __restrict__ aat,
    const float* __restrict__ Wih0, const float* __restrict__ Whh0,
    const float* __restrict__ bih0, const float* __restrict__ bhh0,
    const float* __restrict__ Wih1, const float* __restrict__ Whh1,
    const float* __restrict__ bih1, const float* __restrict__ bhh1,
    const float* __restrict__ fcW,  const float* __restrict__ fcb,
    float* __restrict__ out)
{
    __shared__ int   snbr[SQ][64];
    __shared__ int   scnt[SQ];
    __shared__ float shg[SQ*384];                        // local hgat (7.5 KB)
    __shared__ __align__(16) char uarea[43200];          // B: X[b] slice ; C: v dbuf + sh1f

    const int tid  = threadIdx.x;
    const int w    = tid >> 6;        // wave 0..7
    const int l    = tid & 63;
    const int seq0 = blockIdx.x * SQ;
    const int b    = seq0 / 300, i0 = seq0 - b*300;

    float* Xs = (float*)uarea;

    // ---------- phase A: cooperative X[b] slice load + neighbor lists ----------
    {
        const float* Xg = X + (size_t)b * 10800;
        for (int x = tid; x < 10800; x += 512) Xs[x] = Xg[x];
    }
    if (w < SQ) {                     // wave w builds neighbor list of row i0+w
        int i = i0 + w;
        int c = 0;
        for (int j0 = 0; j0 < 300; j0 += 64) {
            int j = j0 + l;
            bool p = (j < 300) && (A[i*300 + j] != 0.f);
            unsigned long long m = __ballot(p);
            if (p) {
                int pos = __popcll(m & ((1ull << l) - 1ull));
                if (c + pos < 64) snbr[w][c + pos] = j;
            }
            c += __popcll(m);
        }
        if (c > 64) c = 64;
        if (l == 0) scnt[w] = c;
    }
    __syncthreads();

    // ---------- phase B: GAT attention (all 8 waves, max-free softmax, DPP merges) ----------
    {
        const int hh = l >> 3, j8 = l & 7, dd = j8 & 3;
        float wal0=0.f, wal1=0.f, wal2=0.f, war0=0.f, war1=0.f, war2=0.f;
        #pragma unroll
        for (int d4 = 0; d4 < 4; d4++) {
            float av = aat[d4], bv = aat[4+d4];
            const float* wr = Wg + (hh*4+d4)*3;
            wal0 += wr[0]*av; wal1 += wr[1]*av; wal2 += wr[2]*av;
            war0 += wr[0]*bv; war1 += wr[1]*bv; war2 += wr[2]*bv;
        }
        const float* wp = Wg + (hh*4+dd)*3;
        float wp0 = wp[0], wp1 = wp[1], wp2 = wp[2];

        for (int u = 7 - w; u < SQ*12; u += 8) {
            int us = u / 12, t = u - us*12;
            int i = i0 + us;
            int c = scnt[us];

            const float* Xi = Xs + i*36 + t*3;
            float gl = Xi[0]*wal0 + Xi[1]*wal1 + Xi[2]*wal2;

            float s = 0.f, a0 = 0.f, a1 = 0.f, a2 = 0.f;
            for (int kk = j8; kk < c; kk += 8) {
                int j = snbr[us][kk];
                const float* Xj = Xs + j*36 + t*3;
                float y0 = Xj[0], y1 = Xj[1], y2 = Xj[2];
                float e = gl + y0*war0 + y1*war1 + y2*war2;
                e = e > 0.f ? e : 0.2f*e;      // leaky_relu 0.2
                float wt = __expf(e);
                s += wt; a0 += wt*y0; a1 += wt*y1; a2 += wt*y2;
            }
            s  = dppadd1(s);  a0 = dppadd1(a0); a1 = dppadd1(a1); a2 = dppadd1(a2);
            s  = dppadd2(s);  a0 = dppadd2(a0); a1 = dppadd2(a1); a2 = dppadd2(a2);
            s  += __shfl_xor(s, 4, 64);
            a0 += __shfl_xor(a0, 4, 64);
            a1 += __shfl_xor(a1, 4, 64);
            a2 += __shfl_xor(a2, 4, 64);
            if (j8 < 4)
                shg[us*384 + t*32 + hh*4 + dd] = (a0*wp0 + a1*wp1 + a2*wp2) / s;
        }
    }

    // ---------- A-fragments: waves 0-3 = layer 0, waves 4-7 = layer 1 ----------
    const int n16   = l & 15;         // B/D col = seq slot ; A frag row
    const int g     = l >> 4;         // k-group ; D row-quad
    const int wl    = w & 3;
    const int layer = w >> 2;
    const int cA    = wl*8 + g;       // cells owned by this lane
    const int cB    = wl*8 + 4 + g;
    s8v ah[2][2], al[2][2];
    f4v bias[2];
    {
        const float* Wih = layer ? Wih1 : Wih0;
        const float* Whh = layer ? Whh1 : Whh0;
        const float* bi  = layer ? bih1 : bih0;
        const float* bh  = layer ? bhh1 : bhh0;
        #pragma unroll
        for (int tau = 0; tau < 2; tau++) {
            const int arow = (n16 & 3)*32 + wl*8 + tau*4 + (n16 >> 2);   // permuted W row
            const float* si = Wih + arow*32 + g*8;
            const float* sh = Whh + arow*32 + g*8;
            #pragma unroll
            for (int j = 0; j < 8; j++) {
                short h2, l2;
                bsplit(si[j], h2, l2); ah[tau][0][j]=h2; al[tau][0][j]=l2;
                bsplit(sh[j], h2, l2); ah[tau][1][j]=h2; al[tau][1][j]=l2;
            }
            const int cell = wl*8 + tau*4 + g;
            #pragma unroll
            for (int r = 0; r < 4; r++)
                bias[tau][r] = bi[r*32+cell] + bh[r*32+cell];
        }
    }
    __syncthreads();                  // Xs dead; uarea becomes double-buffered v state

    // ---------- phase C layout: vb[buf][lay][hl][16*72] shorts ----------
    short* vb = (short*)uarea;                            // 8 x 1152 shorts = 18432 B
    float* sh1f = (float*)(vb + 8*1152);                  // final h1 for FC (640 B)
    #define VOFF(buf, lay, hl) ((((buf)*2 + (lay))*2 + (hl))*1152)

    { unsigned* vz = (unsigned*)uarea; for (int x = tid; x < 4608; x += 512) vz[x] = 0; }
    __syncthreads();
    if (tid < SQ*32) {                                    // x(0) -> v0[buf0]
        int us = tid >> 5, uc = tid & 31;
        short h2, l2; bsplit(shg[us*384 + uc], h2, l2);
        vb[VOFF(0,0,0) + us*72 + uc] = h2;  vb[VOFF(0,0,1) + us*72 + uc] = l2;
    }
    __syncthreads();

    const int boff = n16 * 144;
    float csA = 0.f, csB = 0.f;
    int cur = 0;

    auto cellup = [&](f4v z, float& cs) -> float {
        cs = sgm(z[1])*cs + sgm(z[0])*tanhq(z[2]);
        return sgm(z[3])*tanhq(cs);
    };

    // ---- prologue (phase -1): layer-0 computes z0(0); h0(0) -> buf1; x(1) -> buf1 ----
    {
        if (layer == 0) {
            f4v zAa, zBb;
            zA2(vb + VOFF(0,0,0), vb + VOFF(0,0,1), ah, al, bias, boff, g, zAa, zBb);
            float hA = cellup(zAa, csA);
            float hB = cellup(zBb, csB);
            short h2, l2;
            bsplit(hA, h2, l2);
            vb[VOFF(1,0,0) + n16*72 + 32 + cA] = h2;  vb[VOFF(1,0,1) + n16*72 + 32 + cA] = l2;
            vb[VOFF(1,1,0) + n16*72 + cA]      = h2;  vb[VOFF(1,1,1) + n16*72 + cA]      = l2;
            bsplit(hB, h2, l2);
            vb[VOFF(1,0,0) + n16*72 + 32 + cB] = h2;  vb[VOFF(1,0,1) + n16*72 + 32 + cB] = l2;
            vb[VOFF(1,1,0) + n16*72 + cB]      = h2;  vb[VOFF(1,1,1) + n16*72 + cB]      = l2;
        }
        if (tid < SQ*32) {                                // x(1)
            int us = tid >> 5, uc = tid & 31;
            short h2, l2; bsplit(shg[us*384 + 32 + uc], h2, l2);
            vb[VOFF(1,0,0) + us*72 + uc] = h2;  vb[VOFF(1,0,1) + us*72 + uc] = l2;
        }
        __syncthreads();
        cur = 1;
    }

    // ---- main loop: phase p = { z0(p+1) on waves 0-3  ||  z1(p) on waves 4-7 } ----
    for (int p = 0; p < 12; p++) {
        const int nxt = cur ^ 1;
        const bool active = (layer == 1) || (p < 11);
        if (active) {
            f4v zAa, zBb;
            zA2(vb + VOFF(cur,layer,0), vb + VOFF(cur,layer,1), ah, al, bias, boff, g, zAa, zBb);
            float hA = cellup(zAa, csA);
            float hB = cellup(zBb, csB);
            short h2, l2;
            if (layer == 0) {                             // h0(p+1) -> v0next.h0, v1next.h0
                bsplit(hA, h2, l2);
                vb[VOFF(nxt,0,0) + n16*72 + 32 + cA] = h2;  vb[VOFF(nxt,0,1) + n16*72 + 32 + cA] = l2;
                vb[VOFF(nxt,1,0) + n16*72 + cA]      = h2;  vb[VOFF(nxt,1,1) + n16*72 + cA]      = l2;
                bsplit(hB, h2, l2);
                vb[VOFF(nxt,0,0) + n16*72 + 32 + cB] = h2;  vb[VOFF(nxt,0,1) + n16*72 + 32 + cB] = l2;
                vb[VOFF(nxt,1,0) + n16*72 + cB]      = h2;  vb[VOFF(nxt,1,1) + n16*72 + cB]      = l2;
            } else {                                      // h1(p) -> v1next.h1
                bsplit(hA, h2, l2);
                vb[VOFF(nxt,1,0) + n16*72 + 32 + cA] = h2;  vb[VOFF(nxt,1,1) + n16*72 + 32 + cA] = l2;
                bsplit(hB, h2, l2);
                vb[VOFF(nxt,1,0) + n16*72 + 32 + cB] = h2;  vb[VOFF(nxt,1,1) + n16*72 + 32 + cB] = l2;
                if (p == 11 && n16 < SQ) { sh1f[n16*32 + cA] = hA; sh1f[n16*32 + cB] = hB; }
            }
        }
        if (tid < SQ*32 && p + 2 < 12) {                  // stage x(p+2) -> v0next.x
            int us = tid >> 5, uc = tid & 31;
            short h2, l2; bsplit(shg[us*384 + (p+2)*32 + uc], h2, l2);
            vb[VOFF(nxt,0,0) + us*72 + uc] = h2;  vb[VOFF(nxt,0,1) + us*72 + uc] = l2;
        }
        __syncthreads();
        cur = nxt;
    }

    // ---- FC: 180 outputs (5 seqs x 36) ----
    if (tid < SQ*36) {
        int s = tid / 36, r = tid - s*36;
        float acc = fcb[r];
        #pragma unroll
        for (int c4 = 0; c4 < 8; c4++) {
            float4 uv = *(const float4*)&fcW[r*32 + 4*c4];
            acc += uv.x*sh1f[s*32+4*c4+0] + uv.y*sh1f[s*32+4*c4+1]
                 + uv.z*sh1f[s*32+4*c4+2] + uv.w*sh1f[s*32+4*c4+3];
        }
        out[(seq0 + s)*36 + r] = acc;
    }
}

extern "C" void kernel_launch(void* const* d_in, const int* in_sizes, int n_in,
                              void* d_out, int out_size, void* d_ws, size_t ws_size,
                              hipStream_t stream)
{
    const float* A    = (const float*)d_in[0];
    const float* X    = (const float*)d_in[1];
    const float* Wg   = (const float*)d_in[2];
    const float* aat  = (const float*)d_in[3];
    const float* Wih0 = (const float*)d_in[4];
    const float* Whh0 = (const float*)d_in[5];
    const float* bih0 = (const float*)d_in[6];
    const float* bhh0 = (const float*)d_in[7];
    const float* Wih1 = (const float*)d_in[8];
    const float* Whh1 = (const float*)d_in[9];
    const float* bih1 = (const float*)d_in[10];
    const float* bhh1 = (const float*)d_in[11];
    const float* fcW  = (const float*)d_in[12];
    const float* fcb  = (const float*)d_in[13];
    float* out = (float*)d_out;

    k_stgat<<<480, 512, 0, stream>>>(A, X, Wg, aat,
                                     Wih0, Whh0, bih0, bhh0,
                                     Wih1, Whh1, bih1, bhh1,
                                     fcW, fcb, out);
}